// Round 8
// baseline (59.752 us; speedup 1.0000x reference)
//
#include <hip/hip_runtime.h>

#define NENT 8192
#define COLS_PB 32                // columns owned per block (one 128B line span)
#define NPHASE 32                 // row phases per block (1024 threads = 32 x 32)
#define ROWS_PP (NENT / NPHASE)   // 256 rows per phase

// pack: (float_bits(val) << 32) | ~row. Values nonneg -> uint order == value
// order; ties -> larger ~row == smaller row == first occurrence (jnp.argmax).
__device__ __forceinline__ unsigned long long pack_vi(float v, int i) {
    return ((unsigned long long)__float_as_uint(v) << 32) | (unsigned)(~i);
}

// One block owns cols [32*cx, 32*cx+32) across ALL rows: no partials, no
// second kernel, no fences. t = p*32 + c: each 32-lane half-wave reads one
// full 128B line per load. 16 waves/CU for latency hiding; NT loads keep
// the 268MB R stream from churning L2.
__global__ __launch_bounds__(1024, 1) void proj_colown_kernel(
    const float* __restrict__ emb, const float* __restrict__ R,
    const int* __restrict__ is_neg_p, float* __restrict__ out) {
    const int t   = threadIdx.x;
    const int c   = t & (COLS_PB - 1);
    const int p   = t >> 5;                 // phase 0..31
    const int cx  = blockIdx.x;
    const int col = cx * COLS_PB + c;
    const int neg = *is_neg_p;              // uniform

    __shared__ float se[NENT];              // full embedding row, 32 KB
    __shared__ unsigned long long red[NPHASE][COLS_PB];  // 8 KB

#pragma unroll
    for (int j = 0; j < NENT / 1024; ++j) se[t + j * 1024] = emb[t + j * 1024];
    __syncthreads();

    const float* rp = R + (size_t)(p * ROWS_PP) * NENT + col;
    const float* ep = se + p * ROWS_PP;

    float best = -1.f;
    int   bk   = 0;   // row index within this phase

#pragma unroll 16
    for (int k = 0; k < ROWS_PP; ++k) {
        float v = __builtin_nontemporal_load(rp + (size_t)k * NENT);
        if (neg) v = 1.f - fminf(1.f, v);   // NEG_SCALE == 1.0
        float pr = ep[k] * v;
        if (pr > best) { best = pr; bk = k; }
    }

    red[p][c] = pack_vi(best, p * ROWS_PP + bk);
    __syncthreads();

    if (t < COLS_PB) {
        unsigned long long b = red[0][t];
#pragma unroll
        for (int q = 1; q < NPHASE; ++q) {
            unsigned long long v = red[q][t];
            b = v > b ? v : b;
        }
        const int oc = cx * COLS_PB + t;
        out[oc]        = __uint_as_float((unsigned)(b >> 32));
        out[NENT + oc] = (float)(~(unsigned)(b & 0xFFFFFFFFull));
    }
}

extern "C" void kernel_launch(void* const* d_in, const int* in_sizes, int n_in,
                              void* d_out, int out_size, void* d_ws, size_t ws_size,
                              hipStream_t stream) {
    const float* emb      = (const float*)d_in[0];
    const float* R        = (const float*)d_in[1];
    const int*   is_neg_p = (const int*)d_in[2];
    float* out            = (float*)d_out;

    proj_colown_kernel<<<NENT / COLS_PB, 1024, 0, stream>>>(emb, R, is_neg_p, out);
}

// Round 9
// 50.607 us; speedup vs baseline: 1.1807x; 1.1807x over previous
//
#include <hip/hip_runtime.h>

#define NENT 8192
#define COLS_PB 32                // columns owned per block (one 128B line span)
#define NPHASE 32                 // row phases per block (1024 threads = 32 x 32)
#define ROWS_PP (NENT / NPHASE)   // 256 rows per phase

// pack: (float_bits(val) << 32) | ~row. Values nonneg -> uint order == value
// order; ties -> larger ~row == smaller row == first occurrence (jnp.argmax).
__device__ __forceinline__ unsigned long long pack_vi(float v, int i) {
    return ((unsigned long long)__float_as_uint(v) << 32) | (unsigned)(~i);
}

// One block owns cols [32*cx, 32*cx+32) across ALL rows: no partials, no
// second kernel, no fences. t = p*32 + c: each 32-lane half-wave reads one
// full 128B line per load. This round: 16 waves/CU, NO nontemporal hints
// (isolating round-8's regression).
__global__ __launch_bounds__(1024, 1) void proj_colown_kernel(
    const float* __restrict__ emb, const float* __restrict__ R,
    const int* __restrict__ is_neg_p, float* __restrict__ out) {
    const int t   = threadIdx.x;
    const int c   = t & (COLS_PB - 1);
    const int p   = t >> 5;                 // phase 0..31
    const int cx  = blockIdx.x;
    const int col = cx * COLS_PB + c;
    const int neg = *is_neg_p;              // uniform

    __shared__ float se[NENT];              // full embedding row, 32 KB
    __shared__ unsigned long long red[NPHASE][COLS_PB];  // 8 KB

#pragma unroll
    for (int j = 0; j < NENT / 1024; ++j) se[t + j * 1024] = emb[t + j * 1024];
    __syncthreads();

    const float* rp = R + (size_t)(p * ROWS_PP) * NENT + col;
    const float* ep = se + p * ROWS_PP;

    float best = -1.f;
    int   bk   = 0;   // row index within this phase

#pragma unroll 16
    for (int k = 0; k < ROWS_PP; ++k) {
        float v = rp[(size_t)k * NENT];
        if (neg) v = 1.f - fminf(1.f, v);   // NEG_SCALE == 1.0
        float pr = ep[k] * v;
        if (pr > best) { best = pr; bk = k; }
    }

    red[p][c] = pack_vi(best, p * ROWS_PP + bk);
    __syncthreads();

    if (t < COLS_PB) {
        unsigned long long b = red[0][t];
#pragma unroll
        for (int q = 1; q < NPHASE; ++q) {
            unsigned long long v = red[q][t];
            b = v > b ? v : b;
        }
        const int oc = cx * COLS_PB + t;
        out[oc]        = __uint_as_float((unsigned)(b >> 32));
        out[NENT + oc] = (float)(~(unsigned)(b & 0xFFFFFFFFull));
    }
}

extern "C" void kernel_launch(void* const* d_in, const int* in_sizes, int n_in,
                              void* d_out, int out_size, void* d_ws, size_t ws_size,
                              hipStream_t stream) {
    const float* emb      = (const float*)d_in[0];
    const float* R        = (const float*)d_in[1];
    const int*   is_neg_p = (const int*)d_in[2];
    float* out            = (float*)d_out;

    proj_colown_kernel<<<NENT / COLS_PB, 1024, 0, stream>>>(emb, R, is_neg_p, out);
}

// Round 10
// 45.234 us; speedup vs baseline: 1.3210x; 1.1188x over previous
//
#include <hip/hip_runtime.h>

#define NENT 8192
#define COLS_PB 32        // columns owned per block (one 128B line span)
#define NPHASE 16         // row phases per block (512 threads = 32 x 16)
#define ROWS_PP (NENT / NPHASE)   // 512 rows per phase

// pack: (float_bits(val) << 32) | ~row. Values nonneg -> uint order == value
// order; ties -> larger ~row == smaller row == first occurrence (jnp.argmax).
__device__ __forceinline__ unsigned long long pack_vi(float v, int i) {
    return ((unsigned long long)__float_as_uint(v) << 32) | (unsigned)(~i);
}

// One block owns cols [32*cx, 32*cx+32) across ALL rows: no partials, no
// second kernel, no fences. t = p*32 + c: lane group 0-31 / 32-63 each read
// one full 128B line per load instruction. 512 threads / 8 waves per block
// proved optimal (R7=45.3 vs R9 1024thr=50.6 vs R8 1024+NT=59.8).
__global__ __launch_bounds__(512, 1) void proj_colown_kernel(
    const float* __restrict__ emb, const float* __restrict__ R,
    const int* __restrict__ is_neg_p, float* __restrict__ out) {
    const int t   = threadIdx.x;
    const int c   = t & (COLS_PB - 1);
    const int p   = t >> 5;                 // phase 0..15
    const int cx  = blockIdx.x;
    const int col = cx * COLS_PB + c;
    const int neg = *is_neg_p;              // uniform

    __shared__ float se[NENT];              // full embedding row, 32 KB
    __shared__ unsigned long long red[NPHASE][COLS_PB];  // 4 KB

#pragma unroll
    for (int j = 0; j < NENT / 512; ++j) se[t + j * 512] = emb[t + j * 512];
    __syncthreads();

    const float* rp = R + (size_t)(p * ROWS_PP) * NENT + col;
    const float* ep = se + p * ROWS_PP;

    float best = -1.f;
    int   bk   = 0;   // row index within this phase

#pragma unroll 16
    for (int k = 0; k < ROWS_PP; ++k) {
        float v = rp[(size_t)k * NENT];
        if (neg) v = 1.f - fminf(1.f, v);   // NEG_SCALE == 1.0
        float pr = ep[k] * v;
        if (pr > best) { best = pr; bk = k; }
    }

    red[p][c] = pack_vi(best, p * ROWS_PP + bk);
    __syncthreads();

    if (t < COLS_PB) {
        unsigned long long b = red[0][t];
#pragma unroll
        for (int q = 1; q < NPHASE; ++q) {
            unsigned long long v = red[q][t];
            b = v > b ? v : b;
        }
        const int oc = cx * COLS_PB + t;
        out[oc]        = __uint_as_float((unsigned)(b >> 32));
        out[NENT + oc] = (float)(~(unsigned)(b & 0xFFFFFFFFull));
    }
}

extern "C" void kernel_launch(void* const* d_in, const int* in_sizes, int n_in,
                              void* d_out, int out_size, void* d_ws, size_t ws_size,
                              hipStream_t stream) {
    const float* emb      = (const float*)d_in[0];
    const float* R        = (const float*)d_in[1];
    const int*   is_neg_p = (const int*)d_in[2];
    float* out            = (float*)d_out;

    proj_colown_kernel<<<NENT / COLS_PB, 512, 0, stream>>>(emb, R, is_neg_p, out);
}